// Round 5
// baseline (364.949 us; speedup 1.0000x reference)
//
#include <hip/hip_runtime.h>
#include <stdint.h>

// DiscreteMarkovDynamics: 5-step Markov jump sim, B=32, L=4096, V=512.
// R1: table precompute + wave-per-position categorical -> 1024 us.
// R2: provable-reject skip (u >= pthr[s] => categorical dead code) -> 250 us.
// R3: split/parallel builds, LDS pthr, PPW=8 -> 125 us.
// R4: fused wide build; ballot-based candidate scan -> 121 us (markov 52).
//     Markov profile: Occ 29% / VALU 45% -> straggler tail (most waves exit
//     instantly, heavy waves run alone at low residency).
// R5: persistent waves + zoned work-stealing: 8192 waves (exact residency)
//     pull 8-position chunks from 16 zone counters (16 zones kills the
//     single-address atomic serialization). build_table unchanged (R4 bits)
//     so its true duration becomes visible in the profile.

#define VOCAB  512
#define EMB    256
#define HID    64
#define NPOS   (32 * 4096)   // B*L = 131072
#define STEPS  5
#define PPW    8             // positions per chunk; PPW*STEPS=40 <= 64 lanes
#define CHUNKS (NPOS / PPW)  // 16384
#define NZONE  16
#define CPZ    (CHUNKS / NZONE)  // 1024 chunks per zone
#define MBLK   2048          // markov blocks: 2048x256 = 8192 waves = residency

// Exact mirror of jax._src.prng.threefry2x32 (20 rounds).
__host__ __device__ __forceinline__ void tf2x32(uint32_t k0, uint32_t k1,
                                                uint32_t x0, uint32_t x1,
                                                uint32_t& o0, uint32_t& o1) {
  uint32_t ks2 = k0 ^ k1 ^ 0x1BD11BDAu;
  x0 += k0; x1 += k1;
#define TFR(r) { x0 += x1; x1 = (x1 << (r)) | (x1 >> (32 - (r))); x1 ^= x0; }
  TFR(13) TFR(15) TFR(26) TFR(6)
  x0 += k1;  x1 += ks2 + 1u;
  TFR(17) TFR(29) TFR(16) TFR(24)
  x0 += ks2; x1 += k0 + 2u;
  TFR(13) TFR(15) TFR(26) TFR(6)
  x0 += k0;  x1 += k1 + 3u;
  TFR(17) TFR(29) TFR(16) TFR(24)
  x0 += k1;  x1 += ks2 + 4u;
  TFR(13) TFR(15) TFR(26) TFR(6)
  x0 += ks2; x1 += k0 + 5u;
#undef TFR
  o0 = x0; o1 = x1;
}

struct Keys {
  uint32_t k1a[STEPS], k1b[STEPS];  // categorical (gumbel) keys per step
  uint32_t k2a[STEPS], k2b[STEPS];  // accept-uniform keys per step
};

// Fused table build (unchanged from R4 except zone-counter zeroing).
__global__ __launch_bounds__(512)
void build_table(const float* __restrict__ emb,
                 const float* __restrict__ W1,
                 const float* __restrict__ b1,
                 const float* __restrict__ W2,
                 const float* __restrict__ b2,
                 float* __restrict__ I,
                 float* __restrict__ pthr,
                 uint32_t* __restrict__ counters) {
  const int s   = blockIdx.x;
  const int tid = threadIdx.x;
  if (s == 0 && tid < NZONE) counters[tid] = 0u;  // for markov work-steal

  __shared__ double part[8][HID];
  __shared__ double hd[HID];
  __shared__ float  redmax[8];

  const int hid = tid & (HID - 1);
  const int kq  = tid >> 6;               // 0..7
  const float* e = emb + s * EMB;
  double acc = 0.0;
#pragma unroll
  for (int k = kq; k < EMB; k += 8)
    acc += (double)e[k] * (double)W1[k * HID + hid];
  part[kq][hid] = acc;
  __syncthreads();
  if (kq == 0) {
    const double a = ((part[0][hid] + part[1][hid]) + (part[2][hid] + part[3][hid]))
                   + ((part[4][hid] + part[5][hid]) + (part[6][hid] + part[7][hid]));
    const float m = (float)a + b1[hid];
    hd[hid] = (double)(m > 0.0f ? m : 0.0f);   // relu
  }
  __syncthreads();

  double acc2 = 0.0;
#pragma unroll
  for (int k = 0; k < HID; ++k)
    acc2 += hd[k] * (double)W2[k * VOCAB + tid];   // coalesced per k
  const float val = (float)acc2 + b2[tid];
  I[s * VOCAB + tid] = val;

  float lmax = val;                        // max is order-insensitive
  for (int off = 32; off > 0; off >>= 1)
    lmax = fmaxf(lmax, __shfl_xor(lmax, off, 64));
  if ((tid & 63) == 0) redmax[tid >> 6] = lmax;
  __syncthreads();
  if (tid == 0) {
    float m = redmax[0];
#pragma unroll
    for (int i = 1; i < 8; ++i) m = fmaxf(m, redmax[i]);
    const float z = (-m) * 0.01f;          // same chain as accept path
    pthr[s] = 1.0f - (float)exp((double)z);// monotone => safe reject bound
  }
}

// Markov kernel: persistent waves, zoned work-stealing over 8-position
// chunks. Per chunk: one ballot finds all candidate (p,t); loop only over
// set bits (~0.9/chunk); on accept, re-ballot that position's future bits.
__global__ __launch_bounds__(256)
void markov_kernel(const int* __restrict__ x_in,
                   const float* __restrict__ I,
                   const float* __restrict__ pthr,
                   int* __restrict__ x_out,
                   uint32_t* __restrict__ counters,
                   Keys K) {
  __shared__ float sp[VOCAB];
  sp[threadIdx.x]       = pthr[threadIdx.x];
  sp[threadIdx.x + 256] = pthr[threadIdx.x + 256];
  __syncthreads();

  const int lane = threadIdx.x & 63;
  const int wid  = (blockIdx.x << 2) | (threadIdx.x >> 6);
  const int zone = wid & (NZONE - 1);
  const int qp = lane / 5;                 // lane q -> (position, step)
  const int qt = lane - qp * 5;
  const float TINYF = 1.17549435e-38f;

  for (;;) {
    int n = 0;
    if (lane == 0) n = (int)atomicAdd(&counters[zone], 1u);
    n = __shfl(n, 0, 64);                  // wave-uniform chunk index
    if (n >= CPZ) break;
    const int base = (zone * CPZ + n) * PPW;

    // Accept uniforms: lane q < 40 holds u for (p=q/5, t=q%5).
    float u40 = 0.0f;
    if (lane < PPW * STEPS) {
      uint32_t w0, w1;
      tf2x32(K.k2a[qt], K.k2b[qt], 0u, (uint32_t)(base + qp), w0, w1);
      u40 = __uint_as_float((((w0 ^ w1) >> 9) | 0x3f800000u)) - 1.0f;
    }
    int scur = (lane < PPW) ? x_in[base + lane] : 0;  // lane p: state of p

    // Candidate mask: u_q < pthr[s_p] (state fixed unless an accept occurs).
    const int s_of_q = __shfl(scur, qp, 64);
    const bool cand = (lane < PPW * STEPS) && (u40 < sp[s_of_q]);
    unsigned long long mask = __ballot(cand);

    while (mask) {
      const int q = (int)__builtin_ctzll(mask);   // wave-uniform
      mask &= mask - 1;
      const int p = q / 5;
      const int t = q - p * 5;
      const int s = __builtin_amdgcn_readfirstlane(__shfl(scur, p, 64));

      // Full categorical (byte-identical to R1..R4 path).
      const float* row = I + s * VOCAB;
      float best = -__builtin_inff();
      int bidx = 0;
      const uint32_t fbase = ((uint32_t)(base + p) << 9) + (uint32_t)lane;
#pragma unroll
      for (int j = 0; j < VOCAB / 64; ++j) {
        const int v = lane + (j << 6);
        uint32_t w0, w1;
        tf2x32(K.k1a[t], K.k1b[t], 0u, fbase + ((uint32_t)j << 6), w0, w1);
        const uint32_t bits = w0 ^ w1;
        float uf = __uint_as_float((bits >> 9) | 0x3f800000u) - 1.0f;
        if (uf == 0.0f) uf = TINYF;
        const float g = -logf(-logf(uf));
        if (v != s) {
          const float val = row[v] + g;
          if (val > best) { best = val; bidx = v; }
        }
      }
      for (int off = 32; off > 0; off >>= 1) {
        const float ob = __shfl_xor(best, off, 64);
        const int   oi = __shfl_xor(bidx, off, 64);
        if (ob > best || (ob == best && oi < bidx)) { best = ob; bidx = oi; }
      }
      bidx = __builtin_amdgcn_readfirstlane(bidx);
      const float rate = row[bidx];
      const float z = (-rate) * 0.01f;
      const float pacc = 1.0f - (float)exp((double)z);  // CR fp32 exp
      const float u = __shfl(u40, q, 64);
      if (u < pacc) {
        if (lane == p) scur = bidx;                     // accept jump
        // Re-evaluate this position's FUTURE steps under the new state.
        const unsigned long long fut =
            (((1ull << (p * 5 + 5)) - 1) & ~((1ull << (q + 1)) - 1));
        const float pnew = sp[bidx];                    // wave-uniform
        const unsigned long long nb = __ballot(u40 < pnew) & fut;
        mask = (mask & ~fut) | nb;
      }
    }
    if (lane < PPW) x_out[base + lane] = scur;
  }
}

extern "C" void kernel_launch(void* const* d_in, const int* in_sizes, int n_in,
                              void* d_out, int out_size, void* d_ws, size_t ws_size,
                              hipStream_t stream) {
  const int*   x   = (const int*)d_in[0];
  const float* emb = (const float*)d_in[1];
  const float* W1  = (const float*)d_in[2];
  const float* b1  = (const float*)d_in[3];
  const float* W2  = (const float*)d_in[4];
  const float* b2  = (const float*)d_in[5];
  float*    I        = (float*)d_ws;                     // 1 MiB
  float*    pthr     = (float*)d_ws + VOCAB * VOCAB;     // +2 KiB
  uint32_t* counters = (uint32_t*)(pthr + VOCAB);        // +64 B
  int* out = (int*)d_out;

  // Host-side key derivation (partitionable scheme):
  //   key(42) = (0,42); split -> S_t = tf(key,(0,t)); (k1,k2) = tf(S_t,(0,j))
  Keys K;
  for (int t = 0; t < STEPS; ++t) {
    uint32_t Sa, Sb;
    tf2x32(0u, 42u, 0u, (uint32_t)t, Sa, Sb);
    tf2x32(Sa, Sb, 0u, 0u, K.k1a[t], K.k1b[t]);
    tf2x32(Sa, Sb, 0u, 1u, K.k2a[t], K.k2b[t]);
  }

  build_table<<<VOCAB, 512, 0, stream>>>(emb, W1, b1, W2, b2, I, pthr, counters);
  markov_kernel<<<MBLK, 256, 0, stream>>>(x, I, pthr, out, counters, K);
}

// Round 6
// 115.987 us; speedup vs baseline: 3.1465x; 3.1465x over previous
//
#include <hip/hip_runtime.h>
#include <stdint.h>

// DiscreteMarkovDynamics: 5-step Markov jump sim, B=32, L=4096, V=512.
// R1: table precompute + wave-per-position categorical -> 1024 us.
// R2: provable-reject skip (u >= pthr[s] => categorical dead code) -> 250 us.
// R3: split/parallel builds, LDS pthr, PPW=8 -> 125 us.
// R4: fused wide build; ballot candidate scan -> 121 us (markov 52).
// R5: zoned work-steal REGRESSED to 293 us: all 16 counters in ONE cacheline
//     -> every atomic serialized cross-XCD on one line. Reverted.
// R6: static schedule, 2-wave blocks (HW backfill = atomic-free balancing),
//     no LDS/barrier; categorical restructured into independent batches
//     (prefetch row, 8x threefry, 8x gumbel) for ILP (R4's VGPR=32 showed
//     the compiler had serialized the j-loop).

#define VOCAB  512
#define EMB    256
#define HID    64
#define NPOS   (32 * 4096)   // B*L = 131072
#define STEPS  5
#define PPW    8             // positions per chunk; PPW*STEPS=40 <= 64 lanes
#define CHUNKS (NPOS / PPW)  // 16384 chunks = 16384 waves, 2 waves/block

// Exact mirror of jax._src.prng.threefry2x32 (20 rounds).
__host__ __device__ __forceinline__ void tf2x32(uint32_t k0, uint32_t k1,
                                                uint32_t x0, uint32_t x1,
                                                uint32_t& o0, uint32_t& o1) {
  uint32_t ks2 = k0 ^ k1 ^ 0x1BD11BDAu;
  x0 += k0; x1 += k1;
#define TFR(r) { x0 += x1; x1 = (x1 << (r)) | (x1 >> (32 - (r))); x1 ^= x0; }
  TFR(13) TFR(15) TFR(26) TFR(6)
  x0 += k1;  x1 += ks2 + 1u;
  TFR(17) TFR(29) TFR(16) TFR(24)
  x0 += ks2; x1 += k0 + 2u;
  TFR(13) TFR(15) TFR(26) TFR(6)
  x0 += k0;  x1 += k1 + 3u;
  TFR(17) TFR(29) TFR(16) TFR(24)
  x0 += k1;  x1 += ks2 + 4u;
  TFR(13) TFR(15) TFR(26) TFR(6)
  x0 += ks2; x1 += k0 + 5u;
#undef TFR
  o0 = x0; o1 = x1;
}

struct Keys {
  uint32_t k1a[STEPS], k1b[STEPS];  // categorical (gumbel) keys per step
  uint32_t k2a[STEPS], k2b[STEPS];  // accept-uniform keys per step
};

// Fused table build (bit-identical to R4/R5's proven kernel, counters dropped).
__global__ __launch_bounds__(512)
void build_table(const float* __restrict__ emb,
                 const float* __restrict__ W1,
                 const float* __restrict__ b1,
                 const float* __restrict__ W2,
                 const float* __restrict__ b2,
                 float* __restrict__ I,
                 float* __restrict__ pthr) {
  const int s   = blockIdx.x;
  const int tid = threadIdx.x;
  __shared__ double part[8][HID];
  __shared__ double hd[HID];
  __shared__ float  redmax[8];

  const int hid = tid & (HID - 1);
  const int kq  = tid >> 6;               // 0..7
  const float* e = emb + s * EMB;
  double acc = 0.0;
#pragma unroll
  for (int k = kq; k < EMB; k += 8)
    acc += (double)e[k] * (double)W1[k * HID + hid];
  part[kq][hid] = acc;
  __syncthreads();
  if (kq == 0) {
    const double a = ((part[0][hid] + part[1][hid]) + (part[2][hid] + part[3][hid]))
                   + ((part[4][hid] + part[5][hid]) + (part[6][hid] + part[7][hid]));
    const float m = (float)a + b1[hid];
    hd[hid] = (double)(m > 0.0f ? m : 0.0f);   // relu
  }
  __syncthreads();

  double acc2 = 0.0;
#pragma unroll
  for (int k = 0; k < HID; ++k)
    acc2 += hd[k] * (double)W2[k * VOCAB + tid];   // coalesced per k
  const float val = (float)acc2 + b2[tid];
  I[s * VOCAB + tid] = val;

  float lmax = val;                        // max is order-insensitive
  for (int off = 32; off > 0; off >>= 1)
    lmax = fmaxf(lmax, __shfl_xor(lmax, off, 64));
  if ((tid & 63) == 0) redmax[tid >> 6] = lmax;
  __syncthreads();
  if (tid == 0) {
    float m = redmax[0];
#pragma unroll
    for (int i = 1; i < 8; ++i) m = fmaxf(m, redmax[i]);
    const float z = (-m) * 0.01f;          // same chain as accept path
    pthr[s] = 1.0f - (float)exp((double)z);// monotone => safe reject bound
  }
}

// Markov kernel: one wave per 8-position chunk, 2 independent waves/block
// (no LDS, no barrier -> HW block backfill load-balances the Poisson tail).
// Per chunk: one ballot finds all candidate (p,t); loop only over set bits
// (~0.9/chunk). Categorical split into independent batches for ILP.
__global__ __launch_bounds__(128, 4)
void markov_kernel(const int* __restrict__ x_in,
                   const float* __restrict__ I,
                   const float* __restrict__ pthr,
                   int* __restrict__ x_out,
                   Keys K) {
  const int lane  = threadIdx.x & 63;
  const int chunk = (blockIdx.x << 1) | (threadIdx.x >> 6);
  const int base  = chunk * PPW;
  const int qp = lane / 5;                 // lane q -> (position, step)
  const int qt = lane - qp * 5;
  const float TINYF = 1.17549435e-38f;

  // States first (load in flight under the threefry below).
  int scur = (lane < PPW) ? x_in[base + lane] : 0;  // lane p: state of p

  // Accept uniforms: lane q < 40 holds u for (p=q/5, t=q%5).
  float u40 = 0.0f;
  if (lane < PPW * STEPS) {
    uint32_t w0, w1;
    tf2x32(K.k2a[qt], K.k2b[qt], 0u, (uint32_t)(base + qp), w0, w1);
    u40 = __uint_as_float((((w0 ^ w1) >> 9) | 0x3f800000u)) - 1.0f;
  }

  // Candidate mask: u_q < pthr[s_p] (state fixed unless an accept occurs).
  const int s_of_q = __shfl(scur, qp, 64);
  const bool cand = (lane < PPW * STEPS) && (u40 < pthr[s_of_q]);
  unsigned long long mask = __ballot(cand);

  while (mask) {
    const int q = (int)__builtin_ctzll(mask);   // wave-uniform
    mask &= mask - 1;
    const int p = q / 5;
    const int t = q - p * 5;
    const int s = __builtin_amdgcn_readfirstlane(__shfl(scur, p, 64));

    // --- Full categorical (bit-identical math to R1..R5; ILP-batched) ---
    const float* row = I + s * VOCAB;
    float rv[8];
#pragma unroll
    for (int j = 0; j < 8; ++j)               // prefetch row values (L2)
      rv[j] = row[lane + (j << 6)];

    const uint32_t fbase = ((uint32_t)(base + p) << 9) + (uint32_t)lane;
    uint32_t bits[8];
#pragma unroll
    for (int j = 0; j < 8; ++j) {             // 8 independent threefry
      uint32_t w0, w1;
      tf2x32(K.k1a[t], K.k1b[t], 0u, fbase + ((uint32_t)j << 6), w0, w1);
      bits[j] = w0 ^ w1;
    }

    float best = -__builtin_inff();
    int bidx = 0;
#pragma unroll
    for (int j = 0; j < 8; ++j) {             // 8 independent gumbel chains
      float ufv = __uint_as_float((bits[j] >> 9) | 0x3f800000u) - 1.0f;
      if (ufv == 0.0f) ufv = TINYF;
      const float g = -logf(-logf(ufv));
      const int v = lane + (j << 6);
      if (v != s) {
        const float val = rv[j] + g;
        if (val > best) { best = val; bidx = v; }
      }
    }
    for (int off = 32; off > 0; off >>= 1) {
      const float ob = __shfl_xor(best, off, 64);
      const int   oi = __shfl_xor(bidx, off, 64);
      if (ob > best || (ob == best && oi < bidx)) { best = ob; bidx = oi; }
    }
    bidx = __builtin_amdgcn_readfirstlane(bidx);
    const float rate = row[bidx];
    const float z = (-rate) * 0.01f;
    const float pacc = 1.0f - (float)exp((double)z);  // CR fp32 exp
    const float u = __shfl(u40, q, 64);
    if (u < pacc) {
      if (lane == p) scur = bidx;                     // accept jump
      // Re-evaluate this position's FUTURE steps under the new state.
      const unsigned long long fut =
          (((1ull << (p * 5 + 5)) - 1) & ~((1ull << (q + 1)) - 1));
      const float pnew = pthr[bidx];                  // scalar (bidx uniform)
      const unsigned long long nb = __ballot(u40 < pnew) & fut;
      mask = (mask & ~fut) | nb;
    }
  }
  if (lane < PPW) x_out[base + lane] = scur;
}

extern "C" void kernel_launch(void* const* d_in, const int* in_sizes, int n_in,
                              void* d_out, int out_size, void* d_ws, size_t ws_size,
                              hipStream_t stream) {
  const int*   x   = (const int*)d_in[0];
  const float* emb = (const float*)d_in[1];
  const float* W1  = (const float*)d_in[2];
  const float* b1  = (const float*)d_in[3];
  const float* W2  = (const float*)d_in[4];
  const float* b2  = (const float*)d_in[5];
  float* I    = (float*)d_ws;                        // 1 MiB
  float* pthr = (float*)d_ws + VOCAB * VOCAB;        // +2 KiB
  int* out = (int*)d_out;

  // Host-side key derivation (partitionable scheme):
  //   key(42) = (0,42); split -> S_t = tf(key,(0,t)); (k1,k2) = tf(S_t,(0,j))
  Keys K;
  for (int t = 0; t < STEPS; ++t) {
    uint32_t Sa, Sb;
    tf2x32(0u, 42u, 0u, (uint32_t)t, Sa, Sb);
    tf2x32(Sa, Sb, 0u, 0u, K.k1a[t], K.k1b[t]);
    tf2x32(Sa, Sb, 0u, 1u, K.k2a[t], K.k2b[t]);
  }

  build_table<<<VOCAB, 512, 0, stream>>>(emb, W1, b1, W2, b2, I, pthr);
  markov_kernel<<<CHUNKS / 2, 128, 0, stream>>>(x, I, pthr, out, K);
}